// Round 16
// baseline (765.949 us; speedup 1.0000x reference)
//
#include <hip/hip_runtime.h>

typedef unsigned short u16;
typedef __bf16 bf16x8 __attribute__((ext_vector_type(8)));
typedef float f32x4 __attribute__((ext_vector_type(4)));
typedef unsigned short u16x8 __attribute__((ext_vector_type(8)));
typedef unsigned int u32x4 __attribute__((ext_vector_type(4)));

#define NNODES 50000
#define NEDGES 640000
#define NGRAPH 256

__device__ __forceinline__ float bf2f(u16 u) {
  unsigned int v = ((unsigned int)u) << 16; float f; __builtin_memcpy(&f, &v, 4); return f;
}
__device__ __forceinline__ u16 f2bf(float f) {
  unsigned int x; __builtin_memcpy(&x, &f, 4);
  unsigned int lsb = (x >> 16) & 1u;
  x += 0x7fffu + lsb;
  return (u16)(x >> 16);
}

// ---------------- safe fallback: zero fp32 output ---------------------------
__global__ void write_zero_f32(float* __restrict__ out, int n) {
  int i = blockIdx.x * 256 + threadIdx.x;
  if (i < n) out[i] = 0.f;
}

// ---------------- zero-init scratch counters --------------------------------
__global__ void zero_counts(int* __restrict__ a, int na, int* __restrict__ b, int nb) {
  int i = blockIdx.x * 256 + threadIdx.x;
  if (i < na) a[i] = 0;
  if (i < nb) b[i] = 0;
}

// ---------------- weight prep: fp32 -> bf16 transpose (B-layout Wt[n][k]) ---
__global__ void prep_weights(const float* __restrict__ node_w, const float* __restrict__ edge_w1,
                             const float* __restrict__ edge_w2, const float* __restrict__ conv_w1,
                             const float* __restrict__ conv_w2,
                             u16* __restrict__ node_wt, u16* __restrict__ edge_w1t,
                             u16* __restrict__ edge_w2t, u16* __restrict__ conv_w1t,
                             u16* __restrict__ conv_w2t) {
  int o = blockIdx.x * 256 + threadIdx.x;
  if (o < 8192) { int n = o >> 6, k = o & 63; node_wt[o] = f2bf(node_w[k * 128 + n]); return; }
  o -= 8192;
  if (o < 4096) { int n = o >> 5, k = o & 31;
                  edge_w1t[o] = (k < 16) ? f2bf(edge_w1[k * 128 + n]) : (u16)0; return; }
  o -= 4096;
  if (o < 16384) { int n = o >> 7, k = o & 127; edge_w2t[o] = f2bf(edge_w2[k * 128 + n]); return; }
  o -= 16384;
  if (o < 65536) { int l = o >> 14, r = o & 16383, n = r >> 7, k = r & 127;
                   conv_w1t[o] = f2bf(conv_w1[l * 16384 + k * 128 + n]); return; }
  o -= 65536;
  { int l = o >> 14, r = o & 16383, n = r >> 7, k = r & 127;
    conv_w2t[o] = f2bf(conv_w2[l * 16384 + k * 128 + n]); }
}

// ---------------- CSR build --------------------------------------------------
__global__ void hist_all(const int* __restrict__ dst, const int* __restrict__ b,
                         int* __restrict__ counts, int* __restrict__ gc, int n) {
  int i = blockIdx.x * 256 + threadIdx.x;
  atomicAdd(&counts[dst[i]], 1);
  if (i < n) atomicAdd(&gc[b[i]], 1);
}
__global__ void scan_a(const int* __restrict__ counts, int* __restrict__ bsums, int n) {
  int b = blockIdx.x, t = threadIdx.x;
  int i0 = b * 1024 + t * 4;
  int s = 0;
#pragma unroll
  for (int j = 0; j < 4; j++) { int i = i0 + j; if (i < n) s += counts[i]; }
  int lane = t & 63, w = t >> 6;
  for (int m = 32; m; m >>= 1) s += __shfl_xor(s, m, 64);
  __shared__ int ws_[4];
  if (lane == 0) ws_[w] = s;
  __syncthreads();
  if (t == 0) bsums[b] = ws_[0] + ws_[1] + ws_[2] + ws_[3];
}
__global__ void scan_b(int* __restrict__ bsums, int* __restrict__ offs, int nb, int n) {
  if (threadIdx.x == 0) {
    int run = 0;
    for (int i = 0; i < nb; i++) { int v = bsums[i]; bsums[i] = run; run += v; }
    offs[n] = run;
  }
}
__global__ void scan_c(const int* __restrict__ counts, const int* __restrict__ boffs,
                       int* __restrict__ offs, int* __restrict__ cursor, int n) {
  int b = blockIdx.x, t = threadIdx.x;
  int i0 = b * 1024 + t * 4;
  int v[4]; int s = 0;
#pragma unroll
  for (int j = 0; j < 4; j++) { v[j] = (i0 + j < n) ? counts[i0 + j] : 0; s += v[j]; }
  int lane = t & 63, w = t >> 6;
  int x = s;
  for (int d = 1; d < 64; d <<= 1) { int y = __shfl_up(x, (unsigned)d, 64); if (lane >= d) x += y; }
  __shared__ int wt_[4];
  if (lane == 63) wt_[w] = x;
  __syncthreads();
  int add = boffs[b];
  for (int i = 0; i < w; i++) add += wt_[i];
  int excl = add + x - s;
#pragma unroll
  for (int j = 0; j < 4; j++) {
    int i = i0 + j;
    if (i < n) { offs[i] = excl; cursor[i] = excl; }
    excl += v[j];
  }
}
__global__ void gscan(const int* __restrict__ gcounts, int* __restrict__ goffs) {
  int t = threadIdx.x;  // 256
  int v = gcounts[t];
  int lane = t & 63, w = t >> 6;
  int x = v;
  for (int d = 1; d < 64; d <<= 1) { int y = __shfl_up(x, (unsigned)d, 64); if (lane >= d) x += y; }
  __shared__ int wt_[4];
  if (lane == 63) wt_[w] = x;
  __syncthreads();
  int add = 0;
  for (int i = 0; i < w; i++) add += wt_[i];
  int incl = add + x;
  goffs[t] = incl - v;
  if (t == 255) goffs[256] = incl;
}
__global__ void scatter_csr(const int* __restrict__ src, const int* __restrict__ dst,
                            int* __restrict__ cursor, int* __restrict__ csr_src,
                            int* __restrict__ csr_eid) {
  int i = blockIdx.x * 256 + threadIdx.x;
  int d = dst[i];
  int p = atomicAdd(&cursor[d], 1);
  csr_src[p] = src[i];
  csr_eid[p] = i;
}

// ---------------- MFMA tile helper (A,B both from LDS) ----------------------
template <int KB, int SA, int SB>
__device__ __forceinline__ void mfma_block(const u16* aL, const u16* bL, int m, int quad,
                                           int rbase, f32x4* acc) {
#pragma unroll
  for (int kb = 0; kb < KB; ++kb) {
    bf16x8 a = *(const bf16x8*)(aL + (rbase + m) * SA + kb * 32 + quad * 8);
#pragma unroll
    for (int nt = 0; nt < 8; ++nt) {
      bf16x8 b = *(const bf16x8*)(bL + (nt * 16 + m) * SB + kb * 32 + quad * 8);
      acc[nt] = __builtin_amdgcn_mfma_f32_16x16x32_bf16(a, b, acc[nt], 0, 0, 0);
    }
  }
}

// ---------------- node encoder: hb = bf16(x @ node_w + node_b) --------------
__global__ __launch_bounds__(256) void node_encode(const float* __restrict__ x,
                                                   const u16* __restrict__ wt,
                                                   const float* __restrict__ nb,
                                                   u16* __restrict__ hb, int n) {
  __shared__ alignas(16) u16 sA[64 * 72];
  __shared__ alignas(16) u16 sW[128 * 72];
  int t = threadIdx.x;
  int row0 = blockIdx.x * 64;
#pragma unroll
  for (int i = 0; i < 4; i++) {
    int idx = t + 256 * i; int r = idx >> 4, c = idx & 15;  // 64 rows x 16 float4 (K=64)
    int grow = row0 + r; if (grow > n - 1) grow = n - 1;
    float4 v = *(const float4*)(x + (size_t)grow * 64 + c * 4);
    ushort4 o; o.x = f2bf(v.x); o.y = f2bf(v.y); o.z = f2bf(v.z); o.w = f2bf(v.w);
    *(ushort4*)&sA[r * 72 + c * 4] = o;
  }
#pragma unroll
  for (int i = 0; i < 4; i++) {
    int idx = t + 256 * i; int nr = idx >> 3, c = idx & 7;  // 128 rows x 8 uint4 (K=64)
    *(uint4*)&sW[nr * 72 + c * 8] = *(const uint4*)(wt + nr * 64 + c * 8);
  }
  __syncthreads();
  int lane = t & 63, w = t >> 6, m = lane & 15, quad = lane >> 4, rbase = w * 16;
  f32x4 acc[8];
  f32x4 z4 = {0.f, 0.f, 0.f, 0.f};
#pragma unroll
  for (int i = 0; i < 8; i++) acc[i] = z4;
  mfma_block<2, 72, 72>(sA, sW, m, quad, rbase, acc);
#pragma unroll
  for (int nt = 0; nt < 8; nt++) {
    int col = nt * 16 + m;
    float bb = nb[col];
    f32x4 a4 = acc[nt];
#pragma unroll
    for (int r = 0; r < 4; r++) {
      int grow = row0 + rbase + quad * 4 + r;
      if (grow < n) hb[(size_t)grow * 128 + col] = f2bf(a4[r] + bb);
    }
  }
}

// ---------------- edge encoder v7: col-split GEMM2, W2 in registers ---------
__global__ __launch_bounds__(256) void edge_encode(const float* __restrict__ ea,
                                                   const u16* __restrict__ w1t,
                                                   const u16* __restrict__ w2t,
                                                   const float* __restrict__ b1,
                                                   const float* __restrict__ b2,
                                                   const int* __restrict__ csr_eid,
                                                   u16* __restrict__ e_perm) {
  __shared__ alignas(16) u16 sA[64 * 48];     // K padded 16->32
  __shared__ alignas(16) u16 sMid[64 * 136];  // GEMM1 out / GEMM2 in / out tile
  int t = threadIdx.x;
  int lane = t & 63, w = t >> 6, m = lane & 15, quad = lane >> 4, rbase = w * 16;
  int s0 = blockIdx.x * 64;

  if (t < 128) {
    int r = t >> 1, c = t & 1;
    uint4 z = {0, 0, 0, 0};
    *(uint4*)&sA[r * 48 + 16 + c * 8] = z;
  }
  {
    int eidv = 0;
    if (lane < 16) eidv = csr_eid[s0 + w * 16 + lane];
    int r = lane >> 2, c = lane & 3;
    int eid = __shfl(eidv, r, 64);
    float4 v = *(const float4*)(ea + (size_t)eid * 16 + c * 4);
    ushort4 o; o.x = f2bf(v.x); o.y = f2bf(v.y); o.z = f2bf(v.z); o.w = f2bf(v.w);
    *(ushort4*)&sA[(w * 16 + r) * 48 + c * 4] = o;
  }
  bf16x8 w1f[8];
  float b1r[8];
#pragma unroll
  for (int nt = 0; nt < 8; nt++) {
    w1f[nt] = *(const bf16x8*)(w1t + (nt * 16 + m) * 32 + quad * 8);
    b1r[nt] = b1[nt * 16 + m];
  }
  __syncthreads();  // b1

  f32x4 z4 = {0.f, 0.f, 0.f, 0.f};
  f32x4 acc[8];
#pragma unroll
  for (int i = 0; i < 8; i++) acc[i] = z4;
  {
    bf16x8 a = *(const bf16x8*)(&sA[(rbase + m) * 48 + quad * 8]);
#pragma unroll
    for (int nt = 0; nt < 8; nt++)
      acc[nt] = __builtin_amdgcn_mfma_f32_16x16x32_bf16(a, w1f[nt], acc[nt], 0, 0, 0);
  }
#pragma unroll
  for (int nt = 0; nt < 8; nt++) {
#pragma unroll
    for (int r = 0; r < 4; r++) {
      float v = fmaxf(acc[nt][r] + b1r[nt], 0.f);
      unsigned int lo = f2bf(v);
      unsigned int hi = __shfl_xor(lo, 1, 64);
      if ((m & 1) == 0) {
        int rr = rbase + quad * 4 + r;
        *(unsigned int*)&sMid[rr * 136 + nt * 16 + m] = lo | (hi << 16);
      }
    }
  }
  bf16x8 w2f[8];
  float b2r[2];
#pragma unroll
  for (int ct = 0; ct < 2; ct++) {
    b2r[ct] = b2[w * 32 + ct * 16 + m];
#pragma unroll
    for (int kb = 0; kb < 4; kb++)
      w2f[ct * 4 + kb] = *(const bf16x8*)(w2t + (size_t)(w * 32 + ct * 16 + m) * 128 + kb * 32 + quad * 8);
  }
  __syncthreads();  // b2

  f32x4 acc2[8];
#pragma unroll
  for (int i = 0; i < 8; i++) acc2[i] = z4;
#pragma unroll
  for (int rt = 0; rt < 4; rt++) {
#pragma unroll
    for (int kb = 0; kb < 4; kb++) {
      bf16x8 a = *(const bf16x8*)(&sMid[(rt * 16 + m) * 136 + kb * 32 + quad * 8]);
      acc2[rt * 2 + 0] = __builtin_amdgcn_mfma_f32_16x16x32_bf16(a, w2f[kb], acc2[rt * 2 + 0], 0, 0, 0);
      acc2[rt * 2 + 1] = __builtin_amdgcn_mfma_f32_16x16x32_bf16(a, w2f[4 + kb], acc2[rt * 2 + 1], 0, 0, 0);
    }
  }
  __syncthreads();  // b3

#pragma unroll
  for (int rt = 0; rt < 4; rt++) {
#pragma unroll
    for (int ct = 0; ct < 2; ct++) {
#pragma unroll
      for (int r = 0; r < 4; r++) {
        float v = acc2[rt * 2 + ct][r] + b2r[ct];
        unsigned int lo = f2bf(v);
        unsigned int hi = __shfl_xor(lo, 1, 64);
        if ((m & 1) == 0) {
          int rr = rt * 16 + quad * 4 + r;
          int col = w * 32 + ct * 16 + m;
          *(unsigned int*)&sMid[rr * 136 + col] = lo | (hi << 16);
        }
      }
    }
  }
  __syncthreads();  // b4
  // contiguous non-temporal write (e_perm is re-read from HBM anyway)
#pragma unroll
  for (int i = 0; i < 4; i++) {
    int idx = t + 256 * i; int r = idx >> 4, c = idx & 15;
    u32x4 val = *(const u32x4*)&sMid[r * 136 + c * 8];
    __builtin_nontemporal_store(val, (u32x4*)(e_perm + (size_t)(s0 + r) * 128 + c * 8));
  }
}

// ---------------- aggregate v5b: quarter-wave per edge, bf16 residual -------
// z[n] = bf16( hb[n] + sum_{e->n} relu(hb[src]+e) ).
__global__ __launch_bounds__(256) void aggregate_k(const u16* __restrict__ hb,
                                                   const u16* __restrict__ e_perm,
                                                   const int* __restrict__ offs,
                                                   const int* __restrict__ csr_src,
                                                   u16* __restrict__ z, int n) {
  int t = threadIdx.x;
  int node = blockIdx.x * 4 + (t >> 6);
  int lane = t & 63;
  if (node >= n) return;
  int q = lane >> 4, li = lane & 15;  // quarter, lane-in-quarter; cols li*8..+7
  int s0 = offs[node], s1 = offs[node + 1];
  float a[8];
#pragma unroll
  for (int j = 0; j < 8; j++) a[j] = 0.f;
  int s = s0 + q;
  for (; s + 8 <= s1; s += 8) {  // edges s and s+4, both valid
    int v0 = csr_src[s], v1 = csr_src[s + 4];
    u16x8 h0 = *(const u16x8*)(hb + (size_t)v0 * 128 + li * 8);
    u16x8 e0 = *(const u16x8*)(e_perm + (size_t)s * 128 + li * 8);
    u16x8 h1 = *(const u16x8*)(hb + (size_t)v1 * 128 + li * 8);
    u16x8 e1 = *(const u16x8*)(e_perm + (size_t)(s + 4) * 128 + li * 8);
#pragma unroll
    for (int j = 0; j < 8; j++) {
      a[j] += fmaxf(bf2f(h0[j]) + bf2f(e0[j]), 0.f);
      a[j] += fmaxf(bf2f(h1[j]) + bf2f(e1[j]), 0.f);
    }
  }
  for (; s < s1; s += 4) {
    int v = csr_src[s];
    u16x8 hv = *(const u16x8*)(hb + (size_t)v * 128 + li * 8);
    u16x8 ev = *(const u16x8*)(e_perm + (size_t)s * 128 + li * 8);
#pragma unroll
    for (int j = 0; j < 8; j++) a[j] += fmaxf(bf2f(hv[j]) + bf2f(ev[j]), 0.f);
  }
#pragma unroll
  for (int j = 0; j < 8; j++) {
    a[j] += __shfl_xor(a[j], 16, 64);
    a[j] += __shfl_xor(a[j], 32, 64);
  }
  if (q == 0) {
    u16x8 hv = *(const u16x8*)(hb + (size_t)node * 128 + li * 8);
    u16x8 o;
#pragma unroll
    for (int j = 0; j < 8; j++) o[j] = f2bf(bf2f(hv[j]) + a[j]);
    *(u16x8*)(z + (size_t)node * 128 + li * 8) = o;
  }
}

// ---------------- conv MLP v2: col-split GEMMs, weights in registers --------
// hb = bf16( relu(BN(relu(z@W1+b1)@W2+b2)) ).
__global__ __launch_bounds__(256) void conv_mlp(const u16* __restrict__ zb,
                                                u16* __restrict__ hb,
                                                const u16* __restrict__ w1t, const u16* __restrict__ w2t,
                                                const float* __restrict__ b1, const float* __restrict__ b2,
                                                const float* __restrict__ gam, const float* __restrict__ bet,
                                                int n) {
  __shared__ alignas(16) u16 sZ[64 * 136];
  __shared__ alignas(16) u16 sMid[64 * 136];
  int t = threadIdx.x;
  int lane = t & 63, w = t >> 6, m = lane & 15, quad = lane >> 4;
  int row0 = blockIdx.x * 64;
#pragma unroll
  for (int i = 0; i < 4; i++) {
    int idx = t + 256 * i; int r = idx >> 4, c = idx & 15;
    int grow = row0 + r; if (grow > n - 1) grow = n - 1;
    *(uint4*)&sZ[r * 136 + c * 8] = *(const uint4*)(zb + (size_t)grow * 128 + c * 8);
  }
  bf16x8 w1f[8];
  float b1r[2];
#pragma unroll
  for (int ct = 0; ct < 2; ct++) {
    b1r[ct] = b1[w * 32 + ct * 16 + m];
#pragma unroll
    for (int kb = 0; kb < 4; kb++)
      w1f[ct * 4 + kb] = *(const bf16x8*)(w1t + (size_t)(w * 32 + ct * 16 + m) * 128 + kb * 32 + quad * 8);
  }
  __syncthreads();  // b1: sZ complete

  f32x4 z4 = {0.f, 0.f, 0.f, 0.f};
  f32x4 acc[8];  // [rt*2+ct]
#pragma unroll
  for (int i = 0; i < 8; i++) acc[i] = z4;
#pragma unroll
  for (int rt = 0; rt < 4; rt++) {
#pragma unroll
    for (int kb = 0; kb < 4; kb++) {
      bf16x8 a = *(const bf16x8*)(&sZ[(rt * 16 + m) * 136 + kb * 32 + quad * 8]);
      acc[rt * 2 + 0] = __builtin_amdgcn_mfma_f32_16x16x32_bf16(a, w1f[kb], acc[rt * 2 + 0], 0, 0, 0);
      acc[rt * 2 + 1] = __builtin_amdgcn_mfma_f32_16x16x32_bf16(a, w1f[4 + kb], acc[rt * 2 + 1], 0, 0, 0);
    }
  }
#pragma unroll
  for (int rt = 0; rt < 4; rt++) {
#pragma unroll
    for (int ct = 0; ct < 2; ct++) {
#pragma unroll
      for (int r = 0; r < 4; r++) {
        float v = fmaxf(acc[rt * 2 + ct][r] + b1r[ct], 0.f);
        unsigned int lo = f2bf(v);
        unsigned int hi = __shfl_xor(lo, 1, 64);
        if ((m & 1) == 0) {
          int rr = rt * 16 + quad * 4 + r;
          int col = w * 32 + ct * 16 + m;
          *(unsigned int*)&sMid[rr * 136 + col] = lo | (hi << 16);
        }
      }
    }
  }
  bf16x8 w2f[8];
  float b2r[2], gamr[2], betr[2];
#pragma unroll
  for (int ct = 0; ct < 2; ct++) {
    int col = w * 32 + ct * 16 + m;
    b2r[ct] = b2[col]; gamr[ct] = gam[col]; betr[ct] = bet[col];
#pragma unroll
    for (int kb = 0; kb < 4; kb++)
      w2f[ct * 4 + kb] = *(const bf16x8*)(w2t + (size_t)col * 128 + kb * 32 + quad * 8);
  }
  __syncthreads();  // b2: sMid complete

  f32x4 acc2[8];
#pragma unroll
  for (int i = 0; i < 8; i++) acc2[i] = z4;
#pragma unroll
  for (int rt = 0; rt < 4; rt++) {
#pragma unroll
    for (int kb = 0; kb < 4; kb++) {
      bf16x8 a = *(const bf16x8*)(&sMid[(rt * 16 + m) * 136 + kb * 32 + quad * 8]);
      acc2[rt * 2 + 0] = __builtin_amdgcn_mfma_f32_16x16x32_bf16(a, w2f[kb], acc2[rt * 2 + 0], 0, 0, 0);
      acc2[rt * 2 + 1] = __builtin_amdgcn_mfma_f32_16x16x32_bf16(a, w2f[4 + kb], acc2[rt * 2 + 1], 0, 0, 0);
    }
  }
  const float bns = 0.99999500003749983f;  // 1/sqrt(1+1e-5)
#pragma unroll
  for (int rt = 0; rt < 4; rt++) {
#pragma unroll
    for (int ct = 0; ct < 2; ct++) {
      int col = w * 32 + ct * 16 + m;
#pragma unroll
      for (int r = 0; r < 4; r++) {
        int grow = row0 + rt * 16 + quad * 4 + r;
        if (grow < n) {
          float v = acc2[rt * 2 + ct][r] + b2r[ct];
          v = v * bns * gamr[ct] + betr[ct];
          hb[(size_t)grow * 128 + col] = f2bf(fmaxf(v, 0.f));
        }
      }
    }
  }
}

// ---------------- fused gate + pooled segment softmax -----------------------
// Per graph g: gate_i = relu(hb_i@W1+b1)@w2+b2 (computed here), then
// softmax-weighted sum of hb rows -> gpool[g].
__global__ __launch_bounds__(256) void pool_k(const u16* __restrict__ hb,
                                              const float* __restrict__ gw1,
                                              const float* __restrict__ gb1,
                                              const float* __restrict__ gw2,
                                              const float* __restrict__ gb2,
                                              const int* __restrict__ goffs,
                                              float* __restrict__ gate,
                                              float* __restrict__ gpool) {
  int g = blockIdx.x, t = threadIdx.x;  // 256 threads
  int s0 = goffs[g], s1 = goffs[g + 1];
  int lane = t & 63, w = t >> 6;
  __shared__ alignas(16) u16 sW1[128 * 64];
  __shared__ alignas(16) u16 sRow[16 * 128];
  __shared__ float red[4];
  __shared__ float fin[2][128];
  // stage gate W1 (fp32 -> bf16), cols=hidden idx
#pragma unroll
  for (int i = 0; i < 8; i++) {
    int idx = t + 256 * i;
    float4 v = *(const float4*)(gw1 + (size_t)idx * 4);
    ushort4 o; o.x = f2bf(v.x); o.y = f2bf(v.y); o.z = f2bf(v.z); o.w = f2bf(v.w);
    *(ushort4*)&sW1[idx * 4] = o;
  }
  float b1v = gb1[lane], w2v = gw2[lane], b2v = gb2[0];
  // compute gates for this segment, 16 nodes per sweep
  for (int base = s0; base < s1; base += 16) {
    int cnt = s1 - base; if (cnt > 16) cnt = 16;
    __syncthreads();  // sRow reuse + (first iter) sW1 ready
    {
      int r = t >> 4, c = t & 15;
      int node = base + r; if (node >= s1) node = s1 - 1;
      *(uint4*)&sRow[r * 128 + c * 8] = *(const uint4*)(hb + (size_t)node * 128 + c * 8);
    }
    __syncthreads();
#pragma unroll
    for (int j = 0; j < 4; j++) {
      int ridx = w * 4 + j;
      if (ridx < cnt) {
        float s = 0.f;
#pragma unroll 8
        for (int k = 0; k < 128; k++) s += bf2f(sRow[ridx * 128 + k]) * bf2f(sW1[k * 64 + lane]);
        float hid = fmaxf(s + b1v, 0.f);
        float p = hid * w2v;
        for (int d = 32; d; d >>= 1) p += __shfl_xor(p, d, 64);
        if (lane == 0) gate[base + ridx] = p + b2v;
      }
    }
  }
  __syncthreads();  // gate[] writes visible block-wide (same L1/L2 path)
  // segment softmax
  float mx = -3.4e38f;
  for (int i = s0 + t; i < s1; i += 256) mx = fmaxf(mx, gate[i]);
  for (int d = 32; d; d >>= 1) mx = fmaxf(mx, __shfl_xor(mx, d, 64));
  if (lane == 0) red[w] = mx;
  __syncthreads();
  mx = fmaxf(fmaxf(red[0], red[1]), fmaxf(red[2], red[3]));
  __syncthreads();
  float sm = 0.f;
  for (int i = s0 + t; i < s1; i += 256) sm += __expf(gate[i] - mx);
  for (int d = 32; d; d >>= 1) sm += __shfl_xor(sm, d, 64);
  if (lane == 0) red[w] = sm;
  __syncthreads();
  sm = red[0] + red[1] + red[2] + red[3];
  int g2 = t >> 7, tc = t & 127;
  float acc = 0.f;
  for (int i = s0 + g2; i < s1; i += 2)
    acc += __expf(gate[i] - mx) * bf2f(hb[(size_t)i * 128 + tc]);
  fin[g2][tc] = acc;
  __syncthreads();
  if (t < 128) gpool[g * 128 + t] = (s1 > s0) ? (fin[0][t] + fin[1][t]) / sm : 0.f;
}

// ---------------- head ------------------------------------------------------
__global__ __launch_bounds__(128) void head_k(const float* __restrict__ gpool,
                                              const float* __restrict__ w1, const float* __restrict__ b1,
                                              const float* __restrict__ w2, const float* __restrict__ b2,
                                              float* __restrict__ out) {
  int g = blockIdx.x, t = threadIdx.x;  // 128
  __shared__ float sg[128];
  __shared__ float shid[128];
  sg[t] = gpool[g * 128 + t];
  __syncthreads();
  float s = 0.f;
  for (int k = 0; k < 128; k++) s += sg[k] * w1[k * 128 + t];
  shid[t] = fmaxf(s + b1[t], 0.f);
  __syncthreads();
  if (t < 5) {
    float o = b2[t];
    for (int k = 0; k < 128; k++) o += shid[k] * w2[k * 5 + t];
    out[g * 5 + t] = o;
  }
}

// ---------------- launcher ---------------------------------------------------
extern "C" void kernel_launch(void* const* d_in, const int* in_sizes, int n_in,
                              void* d_out, int out_size, void* d_ws, size_t ws_size,
                              hipStream_t stream) {
  const int N = NNODES, E = NEDGES, G = NGRAPH;
  const float* x = (const float*)d_in[0];
  const float* edge_attr = (const float*)d_in[1];
  const float* node_w = (const float*)d_in[2];
  const float* node_b = (const float*)d_in[3];
  const float* edge_w1 = (const float*)d_in[4];
  const float* edge_b1 = (const float*)d_in[5];
  const float* edge_w2 = (const float*)d_in[6];
  const float* edge_b2 = (const float*)d_in[7];
  const float* conv_w1 = (const float*)d_in[8];
  const float* conv_b1 = (const float*)d_in[9];
  const float* conv_w2 = (const float*)d_in[10];
  const float* conv_b2 = (const float*)d_in[11];
  const float* bn_gamma = (const float*)d_in[12];
  const float* bn_beta = (const float*)d_in[13];
  const float* gate_w1 = (const float*)d_in[14];
  const float* gate_b1 = (const float*)d_in[15];
  const float* gate_w2 = (const float*)d_in[16];
  const float* gate_b2 = (const float*)d_in[17];
  const float* head_w1 = (const float*)d_in[18];
  const float* head_b1 = (const float*)d_in[19];
  const float* head_w2 = (const float*)d_in[20];
  const float* head_b2 = (const float*)d_in[21];
  const int* eidx = (const int*)d_in[22];
  const int* batch = (const int*)d_in[23];
  const int* esrc = eidx;
  const int* edst = eidx + E;

  char* wp = (char*)d_ws;
  auto alloc = [&](size_t bytes) { char* p = wp; wp += (bytes + 255) & ~(size_t)255; return p; };
  u16* e_perm = (u16*)alloc((size_t)E * 128 * 2);
  u16* hb = (u16*)alloc((size_t)N * 128 * 2);
  u16* zb = (u16*)alloc((size_t)N * 128 * 2);
  float* gate = (float*)alloc((size_t)N * 4);
  float* gpool = (float*)alloc((size_t)G * 128 * 4);
  int* counts = (int*)alloc((size_t)N * 4);
  int* offs = (int*)alloc((size_t)(N + 1) * 4);
  int* cursor = (int*)alloc((size_t)N * 4);
  int* csr_src = (int*)alloc((size_t)E * 4);
  int* csr_eid = (int*)alloc((size_t)E * 4);
  int* bsums = (int*)alloc(64 * 4);
  int* gcounts = (int*)alloc(G * 4);
  int* goffs = (int*)alloc((G + 1) * 4);
  u16* node_wt = (u16*)alloc(8192 * 2);
  u16* edge_w1t = (u16*)alloc(4096 * 2);
  u16* edge_w2t = (u16*)alloc(16384 * 2);
  u16* conv_w1t = (u16*)alloc(65536 * 2);
  u16* conv_w2t = (u16*)alloc(65536 * 2);

  size_t need = (size_t)(wp - (char*)d_ws);
  if (need > ws_size) {
    write_zero_f32<<<(out_size + 255) / 256, 256, 0, stream>>>((float*)d_out, out_size);
    return;
  }

  zero_counts<<<(N + 255) / 256, 256, 0, stream>>>(counts, N, gcounts, G);
  prep_weights<<<624, 256, 0, stream>>>(node_w, edge_w1, edge_w2, conv_w1, conv_w2,
                                        node_wt, edge_w1t, edge_w2t, conv_w1t, conv_w2t);
  hist_all<<<E / 256, 256, 0, stream>>>(edst, batch, counts, gcounts, N);
  scan_a<<<49, 256, 0, stream>>>(counts, bsums, N);
  scan_b<<<1, 64, 0, stream>>>(bsums, offs, 49, N);
  scan_c<<<49, 256, 0, stream>>>(counts, bsums, offs, cursor, N);
  gscan<<<1, 256, 0, stream>>>(gcounts, goffs);
  scatter_csr<<<E / 256, 256, 0, stream>>>(esrc, edst, cursor, csr_src, csr_eid);
  node_encode<<<(N + 63) / 64, 256, 0, stream>>>(x, node_wt, node_b, hb, N);
  edge_encode<<<E / 64, 256, 0, stream>>>(edge_attr, edge_w1t, edge_w2t, edge_b1, edge_b2,
                                          csr_eid, e_perm);
  for (int l = 0; l < 4; l++) {
    aggregate_k<<<(N + 3) / 4, 256, 0, stream>>>(hb, e_perm, offs, csr_src, zb, N);
    conv_mlp<<<(N + 63) / 64, 256, 0, stream>>>(zb, hb, conv_w1t + l * 16384, conv_w2t + l * 16384,
                                                conv_b1 + l * 128, conv_b2 + l * 128,
                                                bn_gamma + l * 128, bn_beta + l * 128, N);
  }
  pool_k<<<G, 256, 0, stream>>>(hb, gate_w1, gate_b1, gate_w2, gate_b2, goffs, gate, gpool);
  head_k<<<G, 128, 0, stream>>>(gpool, head_w1, head_b1, head_w2, head_b2, (float*)d_out);
}

// Round 17
// 707.181 us; speedup vs baseline: 1.0831x; 1.0831x over previous
//
#include <hip/hip_runtime.h>

typedef unsigned short u16;
typedef __bf16 bf16x8 __attribute__((ext_vector_type(8)));
typedef float f32x4 __attribute__((ext_vector_type(4)));
typedef unsigned short u16x8 __attribute__((ext_vector_type(8)));
typedef unsigned int u32x4 __attribute__((ext_vector_type(4)));

#define NNODES 50000
#define NEDGES 640000
#define NGRAPH 256

__device__ __forceinline__ float bf2f(u16 u) {
  unsigned int v = ((unsigned int)u) << 16; float f; __builtin_memcpy(&f, &v, 4); return f;
}
__device__ __forceinline__ u16 f2bf(float f) {
  unsigned int x; __builtin_memcpy(&x, &f, 4);
  unsigned int lsb = (x >> 16) & 1u;
  x += 0x7fffu + lsb;
  return (u16)(x >> 16);
}

// ---------------- safe fallback: zero fp32 output ---------------------------
__global__ void write_zero_f32(float* __restrict__ out, int n) {
  int i = blockIdx.x * 256 + threadIdx.x;
  if (i < n) out[i] = 0.f;
}

// ---------------- zero-init scratch counters --------------------------------
__global__ void zero_counts(int* __restrict__ a, int na, int* __restrict__ b, int nb) {
  int i = blockIdx.x * 256 + threadIdx.x;
  if (i < na) a[i] = 0;
  if (i < nb) b[i] = 0;
}

// ---------------- weight prep: fp32 -> bf16 transpose (B-layout Wt[n][k]) ---
__global__ void prep_weights(const float* __restrict__ node_w, const float* __restrict__ edge_w1,
                             const float* __restrict__ edge_w2, const float* __restrict__ conv_w1,
                             const float* __restrict__ conv_w2,
                             u16* __restrict__ node_wt, u16* __restrict__ edge_w1t,
                             u16* __restrict__ edge_w2t, u16* __restrict__ conv_w1t,
                             u16* __restrict__ conv_w2t) {
  int o = blockIdx.x * 256 + threadIdx.x;
  if (o < 8192) { int n = o >> 6, k = o & 63; node_wt[o] = f2bf(node_w[k * 128 + n]); return; }
  o -= 8192;
  if (o < 4096) { int n = o >> 5, k = o & 31;
                  edge_w1t[o] = (k < 16) ? f2bf(edge_w1[k * 128 + n]) : (u16)0; return; }
  o -= 4096;
  if (o < 16384) { int n = o >> 7, k = o & 127; edge_w2t[o] = f2bf(edge_w2[k * 128 + n]); return; }
  o -= 16384;
  if (o < 65536) { int l = o >> 14, r = o & 16383, n = r >> 7, k = r & 127;
                   conv_w1t[o] = f2bf(conv_w1[l * 16384 + k * 128 + n]); return; }
  o -= 65536;
  { int l = o >> 14, r = o & 16383, n = r >> 7, k = r & 127;
    conv_w2t[o] = f2bf(conv_w2[l * 16384 + k * 128 + n]); }
}

// ---------------- CSR build --------------------------------------------------
__global__ void hist_all(const int* __restrict__ dst, const int* __restrict__ b,
                         int* __restrict__ counts, int* __restrict__ gc, int n) {
  int i = blockIdx.x * 256 + threadIdx.x;
  atomicAdd(&counts[dst[i]], 1);
  if (i < n) atomicAdd(&gc[b[i]], 1);
}
__global__ void scan_a(const int* __restrict__ counts, int* __restrict__ bsums, int n) {
  int b = blockIdx.x, t = threadIdx.x;
  int i0 = b * 1024 + t * 4;
  int s = 0;
#pragma unroll
  for (int j = 0; j < 4; j++) { int i = i0 + j; if (i < n) s += counts[i]; }
  int lane = t & 63, w = t >> 6;
  for (int m = 32; m; m >>= 1) s += __shfl_xor(s, m, 64);
  __shared__ int ws_[4];
  if (lane == 0) ws_[w] = s;
  __syncthreads();
  if (t == 0) bsums[b] = ws_[0] + ws_[1] + ws_[2] + ws_[3];
}
__global__ void scan_b(int* __restrict__ bsums, int* __restrict__ offs, int nb, int n) {
  if (threadIdx.x == 0) {
    int run = 0;
    for (int i = 0; i < nb; i++) { int v = bsums[i]; bsums[i] = run; run += v; }
    offs[n] = run;
  }
}
__global__ void scan_c(const int* __restrict__ counts, const int* __restrict__ boffs,
                       int* __restrict__ offs, int* __restrict__ cursor, int n) {
  int b = blockIdx.x, t = threadIdx.x;
  int i0 = b * 1024 + t * 4;
  int v[4]; int s = 0;
#pragma unroll
  for (int j = 0; j < 4; j++) { v[j] = (i0 + j < n) ? counts[i0 + j] : 0; s += v[j]; }
  int lane = t & 63, w = t >> 6;
  int x = s;
  for (int d = 1; d < 64; d <<= 1) { int y = __shfl_up(x, (unsigned)d, 64); if (lane >= d) x += y; }
  __shared__ int wt_[4];
  if (lane == 63) wt_[w] = x;
  __syncthreads();
  int add = boffs[b];
  for (int i = 0; i < w; i++) add += wt_[i];
  int excl = add + x - s;
#pragma unroll
  for (int j = 0; j < 4; j++) {
    int i = i0 + j;
    if (i < n) { offs[i] = excl; cursor[i] = excl; }
    excl += v[j];
  }
}
__global__ void gscan(const int* __restrict__ gcounts, int* __restrict__ goffs) {
  int t = threadIdx.x;  // 256
  int v = gcounts[t];
  int lane = t & 63, w = t >> 6;
  int x = v;
  for (int d = 1; d < 64; d <<= 1) { int y = __shfl_up(x, (unsigned)d, 64); if (lane >= d) x += y; }
  __shared__ int wt_[4];
  if (lane == 63) wt_[w] = x;
  __syncthreads();
  int add = 0;
  for (int i = 0; i < w; i++) add += wt_[i];
  int incl = add + x;
  goffs[t] = incl - v;
  if (t == 255) goffs[256] = incl;
}
__global__ void scatter_csr(const int* __restrict__ src, const int* __restrict__ dst,
                            int* __restrict__ cursor, int* __restrict__ csr_src,
                            int* __restrict__ csr_eid) {
  int i = blockIdx.x * 256 + threadIdx.x;
  int d = dst[i];
  int p = atomicAdd(&cursor[d], 1);
  csr_src[p] = src[i];
  csr_eid[p] = i;
}

// ---------------- MFMA tile helper (A,B both from LDS) ----------------------
template <int KB, int SA, int SB>
__device__ __forceinline__ void mfma_block(const u16* aL, const u16* bL, int m, int quad,
                                           int rbase, f32x4* acc) {
#pragma unroll
  for (int kb = 0; kb < KB; ++kb) {
    bf16x8 a = *(const bf16x8*)(aL + (rbase + m) * SA + kb * 32 + quad * 8);
#pragma unroll
    for (int nt = 0; nt < 8; ++nt) {
      bf16x8 b = *(const bf16x8*)(bL + (nt * 16 + m) * SB + kb * 32 + quad * 8);
      acc[nt] = __builtin_amdgcn_mfma_f32_16x16x32_bf16(a, b, acc[nt], 0, 0, 0);
    }
  }
}

// ---------------- node encoder: hb = bf16(x @ node_w + node_b) --------------
__global__ __launch_bounds__(256) void node_encode(const float* __restrict__ x,
                                                   const u16* __restrict__ wt,
                                                   const float* __restrict__ nb,
                                                   u16* __restrict__ hb, int n) {
  __shared__ alignas(16) u16 sA[64 * 72];
  __shared__ alignas(16) u16 sW[128 * 72];
  int t = threadIdx.x;
  int row0 = blockIdx.x * 64;
#pragma unroll
  for (int i = 0; i < 4; i++) {
    int idx = t + 256 * i; int r = idx >> 4, c = idx & 15;  // 64 rows x 16 float4 (K=64)
    int grow = row0 + r; if (grow > n - 1) grow = n - 1;
    float4 v = *(const float4*)(x + (size_t)grow * 64 + c * 4);
    ushort4 o; o.x = f2bf(v.x); o.y = f2bf(v.y); o.z = f2bf(v.z); o.w = f2bf(v.w);
    *(ushort4*)&sA[r * 72 + c * 4] = o;
  }
#pragma unroll
  for (int i = 0; i < 4; i++) {
    int idx = t + 256 * i; int nr = idx >> 3, c = idx & 7;  // 128 rows x 8 uint4 (K=64)
    *(uint4*)&sW[nr * 72 + c * 8] = *(const uint4*)(wt + nr * 64 + c * 8);
  }
  __syncthreads();
  int lane = t & 63, w = t >> 6, m = lane & 15, quad = lane >> 4, rbase = w * 16;
  f32x4 acc[8];
  f32x4 z4 = {0.f, 0.f, 0.f, 0.f};
#pragma unroll
  for (int i = 0; i < 8; i++) acc[i] = z4;
  mfma_block<2, 72, 72>(sA, sW, m, quad, rbase, acc);
#pragma unroll
  for (int nt = 0; nt < 8; nt++) {
    int col = nt * 16 + m;
    float bb = nb[col];
    f32x4 a4 = acc[nt];
#pragma unroll
    for (int r = 0; r < 4; r++) {
      int grow = row0 + rbase + quad * 4 + r;
      if (grow < n) hb[(size_t)grow * 128 + col] = f2bf(a4[r] + bb);
    }
  }
}

// ---------------- edge encoder v7: col-split GEMM2, W2 in registers ---------
__global__ __launch_bounds__(256) void edge_encode(const float* __restrict__ ea,
                                                   const u16* __restrict__ w1t,
                                                   const u16* __restrict__ w2t,
                                                   const float* __restrict__ b1,
                                                   const float* __restrict__ b2,
                                                   const int* __restrict__ csr_eid,
                                                   u16* __restrict__ e_perm) {
  __shared__ alignas(16) u16 sA[64 * 48];     // K padded 16->32
  __shared__ alignas(16) u16 sMid[64 * 136];  // GEMM1 out / GEMM2 in / out tile
  int t = threadIdx.x;
  int lane = t & 63, w = t >> 6, m = lane & 15, quad = lane >> 4, rbase = w * 16;
  int s0 = blockIdx.x * 64;

  if (t < 128) {
    int r = t >> 1, c = t & 1;
    uint4 z = {0, 0, 0, 0};
    *(uint4*)&sA[r * 48 + 16 + c * 8] = z;
  }
  {
    int eidv = 0;
    if (lane < 16) eidv = csr_eid[s0 + w * 16 + lane];
    int r = lane >> 2, c = lane & 3;
    int eid = __shfl(eidv, r, 64);
    float4 v = *(const float4*)(ea + (size_t)eid * 16 + c * 4);
    ushort4 o; o.x = f2bf(v.x); o.y = f2bf(v.y); o.z = f2bf(v.z); o.w = f2bf(v.w);
    *(ushort4*)&sA[(w * 16 + r) * 48 + c * 4] = o;
  }
  bf16x8 w1f[8];
  float b1r[8];
#pragma unroll
  for (int nt = 0; nt < 8; nt++) {
    w1f[nt] = *(const bf16x8*)(w1t + (nt * 16 + m) * 32 + quad * 8);
    b1r[nt] = b1[nt * 16 + m];
  }
  __syncthreads();  // b1

  f32x4 z4 = {0.f, 0.f, 0.f, 0.f};
  f32x4 acc[8];
#pragma unroll
  for (int i = 0; i < 8; i++) acc[i] = z4;
  {
    bf16x8 a = *(const bf16x8*)(&sA[(rbase + m) * 48 + quad * 8]);
#pragma unroll
    for (int nt = 0; nt < 8; nt++)
      acc[nt] = __builtin_amdgcn_mfma_f32_16x16x32_bf16(a, w1f[nt], acc[nt], 0, 0, 0);
  }
#pragma unroll
  for (int nt = 0; nt < 8; nt++) {
#pragma unroll
    for (int r = 0; r < 4; r++) {
      float v = fmaxf(acc[nt][r] + b1r[nt], 0.f);
      unsigned int lo = f2bf(v);
      unsigned int hi = __shfl_xor(lo, 1, 64);
      if ((m & 1) == 0) {
        int rr = rbase + quad * 4 + r;
        *(unsigned int*)&sMid[rr * 136 + nt * 16 + m] = lo | (hi << 16);
      }
    }
  }
  bf16x8 w2f[8];
  float b2r[2];
#pragma unroll
  for (int ct = 0; ct < 2; ct++) {
    b2r[ct] = b2[w * 32 + ct * 16 + m];
#pragma unroll
    for (int kb = 0; kb < 4; kb++)
      w2f[ct * 4 + kb] = *(const bf16x8*)(w2t + (size_t)(w * 32 + ct * 16 + m) * 128 + kb * 32 + quad * 8);
  }
  __syncthreads();  // b2

  f32x4 acc2[8];
#pragma unroll
  for (int i = 0; i < 8; i++) acc2[i] = z4;
#pragma unroll
  for (int rt = 0; rt < 4; rt++) {
#pragma unroll
    for (int kb = 0; kb < 4; kb++) {
      bf16x8 a = *(const bf16x8*)(&sMid[(rt * 16 + m) * 136 + kb * 32 + quad * 8]);
      acc2[rt * 2 + 0] = __builtin_amdgcn_mfma_f32_16x16x32_bf16(a, w2f[kb], acc2[rt * 2 + 0], 0, 0, 0);
      acc2[rt * 2 + 1] = __builtin_amdgcn_mfma_f32_16x16x32_bf16(a, w2f[4 + kb], acc2[rt * 2 + 1], 0, 0, 0);
    }
  }
  __syncthreads();  // b3

#pragma unroll
  for (int rt = 0; rt < 4; rt++) {
#pragma unroll
    for (int ct = 0; ct < 2; ct++) {
#pragma unroll
      for (int r = 0; r < 4; r++) {
        float v = acc2[rt * 2 + ct][r] + b2r[ct];
        unsigned int lo = f2bf(v);
        unsigned int hi = __shfl_xor(lo, 1, 64);
        if ((m & 1) == 0) {
          int rr = rt * 16 + quad * 4 + r;
          int col = w * 32 + ct * 16 + m;
          *(unsigned int*)&sMid[rr * 136 + col] = lo | (hi << 16);
        }
      }
    }
  }
  __syncthreads();  // b4
  // contiguous non-temporal write (e_perm is re-read from HBM anyway)
#pragma unroll
  for (int i = 0; i < 4; i++) {
    int idx = t + 256 * i; int r = idx >> 4, c = idx & 15;
    u32x4 val = *(const u32x4*)&sMid[r * 136 + c * 8];
    __builtin_nontemporal_store(val, (u32x4*)(e_perm + (size_t)(s0 + r) * 128 + c * 8));
  }
}

// ---------------- aggregate v5b: quarter-wave per edge, bf16 residual -------
// z[n] = bf16( hb[n] + sum_{e->n} relu(hb[src]+e) ).
__global__ __launch_bounds__(256) void aggregate_k(const u16* __restrict__ hb,
                                                   const u16* __restrict__ e_perm,
                                                   const int* __restrict__ offs,
                                                   const int* __restrict__ csr_src,
                                                   u16* __restrict__ z, int n) {
  int t = threadIdx.x;
  int node = blockIdx.x * 4 + (t >> 6);
  int lane = t & 63;
  if (node >= n) return;
  int q = lane >> 4, li = lane & 15;  // quarter, lane-in-quarter; cols li*8..+7
  int s0 = offs[node], s1 = offs[node + 1];
  float a[8];
#pragma unroll
  for (int j = 0; j < 8; j++) a[j] = 0.f;
  int s = s0 + q;
  for (; s + 8 <= s1; s += 8) {  // edges s and s+4, both valid
    int v0 = csr_src[s], v1 = csr_src[s + 4];
    u16x8 h0 = *(const u16x8*)(hb + (size_t)v0 * 128 + li * 8);
    u16x8 e0 = *(const u16x8*)(e_perm + (size_t)s * 128 + li * 8);
    u16x8 h1 = *(const u16x8*)(hb + (size_t)v1 * 128 + li * 8);
    u16x8 e1 = *(const u16x8*)(e_perm + (size_t)(s + 4) * 128 + li * 8);
#pragma unroll
    for (int j = 0; j < 8; j++) {
      a[j] += fmaxf(bf2f(h0[j]) + bf2f(e0[j]), 0.f);
      a[j] += fmaxf(bf2f(h1[j]) + bf2f(e1[j]), 0.f);
    }
  }
  for (; s < s1; s += 4) {
    int v = csr_src[s];
    u16x8 hv = *(const u16x8*)(hb + (size_t)v * 128 + li * 8);
    u16x8 ev = *(const u16x8*)(e_perm + (size_t)s * 128 + li * 8);
#pragma unroll
    for (int j = 0; j < 8; j++) a[j] += fmaxf(bf2f(hv[j]) + bf2f(ev[j]), 0.f);
  }
#pragma unroll
  for (int j = 0; j < 8; j++) {
    a[j] += __shfl_xor(a[j], 16, 64);
    a[j] += __shfl_xor(a[j], 32, 64);
  }
  if (q == 0) {
    u16x8 hv = *(const u16x8*)(hb + (size_t)node * 128 + li * 8);
    u16x8 o;
#pragma unroll
    for (int j = 0; j < 8; j++) o[j] = f2bf(bf2f(hv[j]) + a[j]);
    *(u16x8*)(z + (size_t)node * 128 + li * 8) = o;
  }
}

// ---------------- conv MLP v2: col-split GEMMs, weights in registers --------
// hb = bf16( relu(BN(relu(z@W1+b1)@W2+b2)) ).
__global__ __launch_bounds__(256) void conv_mlp(const u16* __restrict__ zb,
                                                u16* __restrict__ hb,
                                                const u16* __restrict__ w1t, const u16* __restrict__ w2t,
                                                const float* __restrict__ b1, const float* __restrict__ b2,
                                                const float* __restrict__ gam, const float* __restrict__ bet,
                                                int n) {
  __shared__ alignas(16) u16 sZ[64 * 136];
  __shared__ alignas(16) u16 sMid[64 * 136];
  int t = threadIdx.x;
  int lane = t & 63, w = t >> 6, m = lane & 15, quad = lane >> 4;
  int row0 = blockIdx.x * 64;
#pragma unroll
  for (int i = 0; i < 4; i++) {
    int idx = t + 256 * i; int r = idx >> 4, c = idx & 15;
    int grow = row0 + r; if (grow > n - 1) grow = n - 1;
    *(uint4*)&sZ[r * 136 + c * 8] = *(const uint4*)(zb + (size_t)grow * 128 + c * 8);
  }
  bf16x8 w1f[8];
  float b1r[2];
#pragma unroll
  for (int ct = 0; ct < 2; ct++) {
    b1r[ct] = b1[w * 32 + ct * 16 + m];
#pragma unroll
    for (int kb = 0; kb < 4; kb++)
      w1f[ct * 4 + kb] = *(const bf16x8*)(w1t + (size_t)(w * 32 + ct * 16 + m) * 128 + kb * 32 + quad * 8);
  }
  __syncthreads();  // b1: sZ complete

  f32x4 z4 = {0.f, 0.f, 0.f, 0.f};
  f32x4 acc[8];  // [rt*2+ct]
#pragma unroll
  for (int i = 0; i < 8; i++) acc[i] = z4;
#pragma unroll
  for (int rt = 0; rt < 4; rt++) {
#pragma unroll
    for (int kb = 0; kb < 4; kb++) {
      bf16x8 a = *(const bf16x8*)(&sZ[(rt * 16 + m) * 136 + kb * 32 + quad * 8]);
      acc[rt * 2 + 0] = __builtin_amdgcn_mfma_f32_16x16x32_bf16(a, w1f[kb], acc[rt * 2 + 0], 0, 0, 0);
      acc[rt * 2 + 1] = __builtin_amdgcn_mfma_f32_16x16x32_bf16(a, w1f[4 + kb], acc[rt * 2 + 1], 0, 0, 0);
    }
  }
#pragma unroll
  for (int rt = 0; rt < 4; rt++) {
#pragma unroll
    for (int ct = 0; ct < 2; ct++) {
#pragma unroll
      for (int r = 0; r < 4; r++) {
        float v = fmaxf(acc[rt * 2 + ct][r] + b1r[ct], 0.f);
        unsigned int lo = f2bf(v);
        unsigned int hi = __shfl_xor(lo, 1, 64);
        if ((m & 1) == 0) {
          int rr = rt * 16 + quad * 4 + r;
          int col = w * 32 + ct * 16 + m;
          *(unsigned int*)&sMid[rr * 136 + col] = lo | (hi << 16);
        }
      }
    }
  }
  bf16x8 w2f[8];
  float b2r[2], gamr[2], betr[2];
#pragma unroll
  for (int ct = 0; ct < 2; ct++) {
    int col = w * 32 + ct * 16 + m;
    b2r[ct] = b2[col]; gamr[ct] = gam[col]; betr[ct] = bet[col];
#pragma unroll
    for (int kb = 0; kb < 4; kb++)
      w2f[ct * 4 + kb] = *(const bf16x8*)(w2t + (size_t)col * 128 + kb * 32 + quad * 8);
  }
  __syncthreads();  // b2: sMid complete

  f32x4 acc2[8];
#pragma unroll
  for (int i = 0; i < 8; i++) acc2[i] = z4;
#pragma unroll
  for (int rt = 0; rt < 4; rt++) {
#pragma unroll
    for (int kb = 0; kb < 4; kb++) {
      bf16x8 a = *(const bf16x8*)(&sMid[(rt * 16 + m) * 136 + kb * 32 + quad * 8]);
      acc2[rt * 2 + 0] = __builtin_amdgcn_mfma_f32_16x16x32_bf16(a, w2f[kb], acc2[rt * 2 + 0], 0, 0, 0);
      acc2[rt * 2 + 1] = __builtin_amdgcn_mfma_f32_16x16x32_bf16(a, w2f[4 + kb], acc2[rt * 2 + 1], 0, 0, 0);
    }
  }
  const float bns = 0.99999500003749983f;  // 1/sqrt(1+1e-5)
#pragma unroll
  for (int rt = 0; rt < 4; rt++) {
#pragma unroll
    for (int ct = 0; ct < 2; ct++) {
      int col = w * 32 + ct * 16 + m;
#pragma unroll
      for (int r = 0; r < 4; r++) {
        int grow = row0 + rt * 16 + quad * 4 + r;
        if (grow < n) {
          float v = acc2[rt * 2 + ct][r] + b2r[ct];
          v = v * bns * gamr[ct] + betr[ct];
          hb[(size_t)grow * 128 + col] = f2bf(fmaxf(v, 0.f));
        }
      }
    }
  }
}

// ---------------- gate: gate[n] = relu(hb@W1+b1)@w2 + b2, 16 nodes/block ----
__global__ __launch_bounds__(256) void gate_k(const u16* __restrict__ hb, const float* __restrict__ w1,
                                              const float* __restrict__ b1, const float* __restrict__ w2,
                                              const float* __restrict__ b2, float* __restrict__ gate) {
  __shared__ alignas(16) u16 sW1[128 * 64];
  __shared__ alignas(16) u16 sRow[16 * 128];
  int t = threadIdx.x;
  int nbase = blockIdx.x * 16;
#pragma unroll
  for (int i = 0; i < 8; i++) {
    int idx = t + 256 * i;  // 2048 chunks-of-4 = 8192 weights
    float4 v = *(const float4*)(w1 + (size_t)idx * 4);
    ushort4 o; o.x = f2bf(v.x); o.y = f2bf(v.y); o.z = f2bf(v.z); o.w = f2bf(v.w);
    *(ushort4*)&sW1[idx * 4] = o;
  }
  {
    int r = t >> 4, c = t & 15;  // 16 rows x 16 uint4
    *(uint4*)&sRow[r * 128 + c * 8] = *(const uint4*)(hb + (size_t)(nbase + r) * 128 + c * 8);
  }
  __syncthreads();
  int lane = t & 63, w = t >> 6;
  float b1v = b1[lane], w2v = w2[lane], b2v = b2[0];
#pragma unroll
  for (int j = 0; j < 4; j++) {
    int node = w * 4 + j;
    float s = 0.f;
#pragma unroll 8
    for (int k = 0; k < 128; k++) s += bf2f(sRow[node * 128 + k]) * bf2f(sW1[k * 64 + lane]);
    float hid = fmaxf(s + b1v, 0.f);
    float p = hid * w2v;
    for (int d = 32; d; d >>= 1) p += __shfl_xor(p, d, 64);
    if (lane == 0) gate[nbase + node] = p + b2v;
  }
}

// ---------------- pooled segment softmax (256 threads, parity-split) --------
__global__ __launch_bounds__(256) void pool_k(const float* __restrict__ gate,
                                              const u16* __restrict__ hb,
                                              const int* __restrict__ goffs,
                                              float* __restrict__ gpool) {
  int g = blockIdx.x, t = threadIdx.x;  // 256 threads
  int s0 = goffs[g], s1 = goffs[g + 1];
  int lane = t & 63, w = t >> 6;
  __shared__ float red[4];
  __shared__ float fin[2][128];
  float mx = -3.4e38f;
  for (int i = s0 + t; i < s1; i += 256) mx = fmaxf(mx, gate[i]);
  for (int d = 32; d; d >>= 1) mx = fmaxf(mx, __shfl_xor(mx, d, 64));
  if (lane == 0) red[w] = mx;
  __syncthreads();
  mx = fmaxf(fmaxf(red[0], red[1]), fmaxf(red[2], red[3]));
  __syncthreads();
  float sm = 0.f;
  for (int i = s0 + t; i < s1; i += 256) sm += __expf(gate[i] - mx);
  for (int d = 32; d; d >>= 1) sm += __shfl_xor(sm, d, 64);
  if (lane == 0) red[w] = sm;
  __syncthreads();
  sm = red[0] + red[1] + red[2] + red[3];
  int g2 = t >> 7, tc = t & 127;
  float acc = 0.f;
  for (int i = s0 + g2; i < s1; i += 2)
    acc += __expf(gate[i] - mx) * bf2f(hb[(size_t)i * 128 + tc]);
  fin[g2][tc] = acc;
  __syncthreads();
  if (t < 128) gpool[g * 128 + t] = (s1 > s0) ? (fin[0][t] + fin[1][t]) / sm : 0.f;
}

// ---------------- head ------------------------------------------------------
__global__ __launch_bounds__(128) void head_k(const float* __restrict__ gpool,
                                              const float* __restrict__ w1, const float* __restrict__ b1,
                                              const float* __restrict__ w2, const float* __restrict__ b2,
                                              float* __restrict__ out) {
  int g = blockIdx.x, t = threadIdx.x;  // 128
  __shared__ float sg[128];
  __shared__ float shid[128];
  sg[t] = gpool[g * 128 + t];
  __syncthreads();
  float s = 0.f;
  for (int k = 0; k < 128; k++) s += sg[k] * w1[k * 128 + t];
  shid[t] = fmaxf(s + b1[t], 0.f);
  __syncthreads();
  if (t < 5) {
    float o = b2[t];
    for (int k = 0; k < 128; k++) o += shid[k] * w2[k * 5 + t];
    out[g * 5 + t] = o;
  }
}

// ---------------- launcher ---------------------------------------------------
extern "C" void kernel_launch(void* const* d_in, const int* in_sizes, int n_in,
                              void* d_out, int out_size, void* d_ws, size_t ws_size,
                              hipStream_t stream) {
  const int N = NNODES, E = NEDGES, G = NGRAPH;
  const float* x = (const float*)d_in[0];
  const float* edge_attr = (const float*)d_in[1];
  const float* node_w = (const float*)d_in[2];
  const float* node_b = (const float*)d_in[3];
  const float* edge_w1 = (const float*)d_in[4];
  const float* edge_b1 = (const float*)d_in[5];
  const float* edge_w2 = (const float*)d_in[6];
  const float* edge_b2 = (const float*)d_in[7];
  const float* conv_w1 = (const float*)d_in[8];
  const float* conv_b1 = (const float*)d_in[9];
  const float* conv_w2 = (const float*)d_in[10];
  const float* conv_b2 = (const float*)d_in[11];
  const float* bn_gamma = (const float*)d_in[12];
  const float* bn_beta = (const float*)d_in[13];
  const float* gate_w1 = (const float*)d_in[14];
  const float* gate_b1 = (const float*)d_in[15];
  const float* gate_w2 = (const float*)d_in[16];
  const float* gate_b2 = (const float*)d_in[17];
  const float* head_w1 = (const float*)d_in[18];
  const float* head_b1 = (const float*)d_in[19];
  const float* head_w2 = (const float*)d_in[20];
  const float* head_b2 = (const float*)d_in[21];
  const int* eidx = (const int*)d_in[22];
  const int* batch = (const int*)d_in[23];
  const int* esrc = eidx;
  const int* edst = eidx + E;

  char* wp = (char*)d_ws;
  auto alloc = [&](size_t bytes) { char* p = wp; wp += (bytes + 255) & ~(size_t)255; return p; };
  u16* e_perm = (u16*)alloc((size_t)E * 128 * 2);
  u16* hb = (u16*)alloc((size_t)(N + 16) * 128 * 2);  // +pad for gate tile overread
  u16* zb = (u16*)alloc((size_t)N * 128 * 2);
  float* gate = (float*)alloc((size_t)N * 4);
  float* gpool = (float*)alloc((size_t)G * 128 * 4);
  int* counts = (int*)alloc((size_t)N * 4);
  int* offs = (int*)alloc((size_t)(N + 1) * 4);
  int* cursor = (int*)alloc((size_t)N * 4);
  int* csr_src = (int*)alloc((size_t)E * 4);
  int* csr_eid = (int*)alloc((size_t)E * 4);
  int* bsums = (int*)alloc(64 * 4);
  int* gcounts = (int*)alloc(G * 4);
  int* goffs = (int*)alloc((G + 1) * 4);
  u16* node_wt = (u16*)alloc(8192 * 2);
  u16* edge_w1t = (u16*)alloc(4096 * 2);
  u16* edge_w2t = (u16*)alloc(16384 * 2);
  u16* conv_w1t = (u16*)alloc(65536 * 2);
  u16* conv_w2t = (u16*)alloc(65536 * 2);

  size_t need = (size_t)(wp - (char*)d_ws);
  if (need > ws_size) {
    write_zero_f32<<<(out_size + 255) / 256, 256, 0, stream>>>((float*)d_out, out_size);
    return;
  }

  zero_counts<<<(N + 255) / 256, 256, 0, stream>>>(counts, N, gcounts, G);
  prep_weights<<<624, 256, 0, stream>>>(node_w, edge_w1, edge_w2, conv_w1, conv_w2,
                                        node_wt, edge_w1t, edge_w2t, conv_w1t, conv_w2t);
  hist_all<<<E / 256, 256, 0, stream>>>(edst, batch, counts, gcounts, N);
  scan_a<<<49, 256, 0, stream>>>(counts, bsums, N);
  scan_b<<<1, 64, 0, stream>>>(bsums, offs, 49, N);
  scan_c<<<49, 256, 0, stream>>>(counts, bsums, offs, cursor, N);
  gscan<<<1, 256, 0, stream>>>(gcounts, goffs);
  scatter_csr<<<E / 256, 256, 0, stream>>>(esrc, edst, cursor, csr_src, csr_eid);
  node_encode<<<(N + 63) / 64, 256, 0, stream>>>(x, node_wt, node_b, hb, N);
  edge_encode<<<E / 64, 256, 0, stream>>>(edge_attr, edge_w1t, edge_w2t, edge_b1, edge_b2,
                                          csr_eid, e_perm);
  for (int l = 0; l < 4; l++) {
    aggregate_k<<<(N + 3) / 4, 256, 0, stream>>>(hb, e_perm, offs, csr_src, zb, N);
    conv_mlp<<<(N + 63) / 64, 256, 0, stream>>>(zb, hb, conv_w1t + l * 16384, conv_w2t + l * 16384,
                                                conv_b1 + l * 128, conv_b2 + l * 128,
                                                bn_gamma + l * 128, bn_beta + l * 128, N);
  }
  gate_k<<<(N + 15) / 16, 256, 0, stream>>>(hb, gate_w1, gate_b1, gate_w2, gate_b2, gate);
  pool_k<<<G, 256, 0, stream>>>(gate, hb, goffs, gpool);
  head_k<<<G, 128, 0, stream>>>(gpool, head_w1, head_b1, head_w2, head_b2, (float*)d_out);
}

// Round 18
// 701.306 us; speedup vs baseline: 1.0922x; 1.0084x over previous
//
#include <hip/hip_runtime.h>

typedef unsigned short u16;
typedef __bf16 bf16x8 __attribute__((ext_vector_type(8)));
typedef float f32x4 __attribute__((ext_vector_type(4)));
typedef unsigned short u16x8 __attribute__((ext_vector_type(8)));

#define NNODES 50000
#define NEDGES 640000
#define NGRAPH 256

__device__ __forceinline__ float bf2f(u16 u) {
  unsigned int v = ((unsigned int)u) << 16; float f; __builtin_memcpy(&f, &v, 4); return f;
}
__device__ __forceinline__ u16 f2bf(float f) {
  unsigned int x; __builtin_memcpy(&x, &f, 4);
  unsigned int lsb = (x >> 16) & 1u;
  x += 0x7fffu + lsb;
  return (u16)(x >> 16);
}

// ---------------- safe fallback: zero fp32 output ---------------------------
__global__ void write_zero_f32(float* __restrict__ out, int n) {
  int i = blockIdx.x * 256 + threadIdx.x;
  if (i < n) out[i] = 0.f;
}

// ---------------- zero-init scratch counters --------------------------------
__global__ void zero_counts(int* __restrict__ a, int na, int* __restrict__ b, int nb) {
  int i = blockIdx.x * 256 + threadIdx.x;
  if (i < na) a[i] = 0;
  if (i < nb) b[i] = 0;
}

// ---------------- weight prep: fp32 -> bf16 transpose (B-layout Wt[n][k]) ---
__global__ void prep_weights(const float* __restrict__ node_w, const float* __restrict__ edge_w1,
                             const float* __restrict__ edge_w2, const float* __restrict__ conv_w1,
                             const float* __restrict__ conv_w2,
                             u16* __restrict__ node_wt, u16* __restrict__ edge_w1t,
                             u16* __restrict__ edge_w2t, u16* __restrict__ conv_w1t,
                             u16* __restrict__ conv_w2t) {
  int o = blockIdx.x * 256 + threadIdx.x;
  if (o < 8192) { int n = o >> 6, k = o & 63; node_wt[o] = f2bf(node_w[k * 128 + n]); return; }
  o -= 8192;
  if (o < 4096) { int n = o >> 5, k = o & 31;
                  edge_w1t[o] = (k < 16) ? f2bf(edge_w1[k * 128 + n]) : (u16)0; return; }
  o -= 4096;
  if (o < 16384) { int n = o >> 7, k = o & 127; edge_w2t[o] = f2bf(edge_w2[k * 128 + n]); return; }
  o -= 16384;
  if (o < 65536) { int l = o >> 14, r = o & 16383, n = r >> 7, k = r & 127;
                   conv_w1t[o] = f2bf(conv_w1[l * 16384 + k * 128 + n]); return; }
  o -= 65536;
  { int l = o >> 14, r = o & 16383, n = r >> 7, k = r & 127;
    conv_w2t[o] = f2bf(conv_w2[l * 16384 + k * 128 + n]); }
}

// ---------------- CSR build --------------------------------------------------
__global__ void hist_all(const int* __restrict__ dst, const int* __restrict__ b,
                         int* __restrict__ counts, int* __restrict__ gc, int n) {
  int i = blockIdx.x * 256 + threadIdx.x;
  atomicAdd(&counts[dst[i]], 1);
  if (i < n) atomicAdd(&gc[b[i]], 1);
}
__global__ void scan_a(const int* __restrict__ counts, int* __restrict__ bsums, int n) {
  int b = blockIdx.x, t = threadIdx.x;
  int i0 = b * 1024 + t * 4;
  int s = 0;
#pragma unroll
  for (int j = 0; j < 4; j++) { int i = i0 + j; if (i < n) s += counts[i]; }
  int lane = t & 63, w = t >> 6;
  for (int m = 32; m; m >>= 1) s += __shfl_xor(s, m, 64);
  __shared__ int ws_[4];
  if (lane == 0) ws_[w] = s;
  __syncthreads();
  if (t == 0) bsums[b] = ws_[0] + ws_[1] + ws_[2] + ws_[3];
}
__global__ void scan_b(int* __restrict__ bsums, int* __restrict__ offs, int nb, int n) {
  if (threadIdx.x == 0) {
    int run = 0;
    for (int i = 0; i < nb; i++) { int v = bsums[i]; bsums[i] = run; run += v; }
    offs[n] = run;
  }
}
__global__ void scan_c(const int* __restrict__ counts, const int* __restrict__ boffs,
                       int* __restrict__ offs, int* __restrict__ cursor, int n) {
  int b = blockIdx.x, t = threadIdx.x;
  int i0 = b * 1024 + t * 4;
  int v[4]; int s = 0;
#pragma unroll
  for (int j = 0; j < 4; j++) { v[j] = (i0 + j < n) ? counts[i0 + j] : 0; s += v[j]; }
  int lane = t & 63, w = t >> 6;
  int x = s;
  for (int d = 1; d < 64; d <<= 1) { int y = __shfl_up(x, (unsigned)d, 64); if (lane >= d) x += y; }
  __shared__ int wt_[4];
  if (lane == 63) wt_[w] = x;
  __syncthreads();
  int add = boffs[b];
  for (int i = 0; i < w; i++) add += wt_[i];
  int excl = add + x - s;
#pragma unroll
  for (int j = 0; j < 4; j++) {
    int i = i0 + j;
    if (i < n) { offs[i] = excl; cursor[i] = excl; }
    excl += v[j];
  }
}
__global__ void gscan(const int* __restrict__ gcounts, int* __restrict__ goffs) {
  int t = threadIdx.x;  // 256
  int v = gcounts[t];
  int lane = t & 63, w = t >> 6;
  int x = v;
  for (int d = 1; d < 64; d <<= 1) { int y = __shfl_up(x, (unsigned)d, 64); if (lane >= d) x += y; }
  __shared__ int wt_[4];
  if (lane == 63) wt_[w] = x;
  __syncthreads();
  int add = 0;
  for (int i = 0; i < w; i++) add += wt_[i];
  int incl = add + x;
  goffs[t] = incl - v;
  if (t == 255) goffs[256] = incl;
}
__global__ void scatter_csr(const int* __restrict__ src, const int* __restrict__ dst,
                            int* __restrict__ cursor, int* __restrict__ csr_src,
                            int* __restrict__ csr_eid) {
  int i = blockIdx.x * 256 + threadIdx.x;
  int d = dst[i];
  int p = atomicAdd(&cursor[d], 1);
  csr_src[p] = src[i];
  csr_eid[p] = i;
}

// ---------------- MFMA tile helper (A,B both from LDS) ----------------------
template <int KB, int SA, int SB>
__device__ __forceinline__ void mfma_block(const u16* aL, const u16* bL, int m, int quad,
                                           int rbase, f32x4* acc) {
#pragma unroll
  for (int kb = 0; kb < KB; ++kb) {
    bf16x8 a = *(const bf16x8*)(aL + (rbase + m) * SA + kb * 32 + quad * 8);
#pragma unroll
    for (int nt = 0; nt < 8; ++nt) {
      bf16x8 b = *(const bf16x8*)(bL + (nt * 16 + m) * SB + kb * 32 + quad * 8);
      acc[nt] = __builtin_amdgcn_mfma_f32_16x16x32_bf16(a, b, acc[nt], 0, 0, 0);
    }
  }
}

// ---------------- node encoder: hb = bf16(x @ node_w + node_b) --------------
__global__ __launch_bounds__(256) void node_encode(const float* __restrict__ x,
                                                   const u16* __restrict__ wt,
                                                   const float* __restrict__ nb,
                                                   u16* __restrict__ hb, int n) {
  __shared__ alignas(16) u16 sA[64 * 72];
  __shared__ alignas(16) u16 sW[128 * 72];
  int t = threadIdx.x;
  int row0 = blockIdx.x * 64;
#pragma unroll
  for (int i = 0; i < 4; i++) {
    int idx = t + 256 * i; int r = idx >> 4, c = idx & 15;  // 64 rows x 16 float4 (K=64)
    int grow = row0 + r; if (grow > n - 1) grow = n - 1;
    float4 v = *(const float4*)(x + (size_t)grow * 64 + c * 4);
    ushort4 o; o.x = f2bf(v.x); o.y = f2bf(v.y); o.z = f2bf(v.z); o.w = f2bf(v.w);
    *(ushort4*)&sA[r * 72 + c * 4] = o;
  }
#pragma unroll
  for (int i = 0; i < 4; i++) {
    int idx = t + 256 * i; int nr = idx >> 3, c = idx & 7;  // 128 rows x 8 uint4 (K=64)
    *(uint4*)&sW[nr * 72 + c * 8] = *(const uint4*)(wt + nr * 64 + c * 8);
  }
  __syncthreads();
  int lane = t & 63, w = t >> 6, m = lane & 15, quad = lane >> 4, rbase = w * 16;
  f32x4 acc[8];
  f32x4 z4 = {0.f, 0.f, 0.f, 0.f};
#pragma unroll
  for (int i = 0; i < 8; i++) acc[i] = z4;
  mfma_block<2, 72, 72>(sA, sW, m, quad, rbase, acc);
#pragma unroll
  for (int nt = 0; nt < 8; nt++) {
    int col = nt * 16 + m;
    float bb = nb[col];
    f32x4 a4 = acc[nt];
#pragma unroll
    for (int r = 0; r < 4; r++) {
      int grow = row0 + rbase + quad * 4 + r;
      if (grow < n) hb[(size_t)grow * 128 + col] = f2bf(a4[r] + bb);
    }
  }
}

// ---------------- edge encoder v7: col-split GEMM2, W2 in registers ---------
__global__ __launch_bounds__(256) void edge_encode(const float* __restrict__ ea,
                                                   const u16* __restrict__ w1t,
                                                   const u16* __restrict__ w2t,
                                                   const float* __restrict__ b1,
                                                   const float* __restrict__ b2,
                                                   const int* __restrict__ csr_eid,
                                                   u16* __restrict__ e_perm) {
  __shared__ alignas(16) u16 sA[64 * 48];     // K padded 16->32
  __shared__ alignas(16) u16 sMid[64 * 136];  // GEMM1 out / GEMM2 in / out tile
  int t = threadIdx.x;
  int lane = t & 63, w = t >> 6, m = lane & 15, quad = lane >> 4, rbase = w * 16;
  int s0 = blockIdx.x * 64;

  if (t < 128) {
    int r = t >> 1, c = t & 1;
    uint4 z = {0, 0, 0, 0};
    *(uint4*)&sA[r * 48 + 16 + c * 8] = z;
  }
  {
    int eidv = 0;
    if (lane < 16) eidv = csr_eid[s0 + w * 16 + lane];
    int r = lane >> 2, c = lane & 3;
    int eid = __shfl(eidv, r, 64);
    float4 v = *(const float4*)(ea + (size_t)eid * 16 + c * 4);
    ushort4 o; o.x = f2bf(v.x); o.y = f2bf(v.y); o.z = f2bf(v.z); o.w = f2bf(v.w);
    *(ushort4*)&sA[(w * 16 + r) * 48 + c * 4] = o;
  }
  bf16x8 w1f[8];
  float b1r[8];
#pragma unroll
  for (int nt = 0; nt < 8; nt++) {
    w1f[nt] = *(const bf16x8*)(w1t + (nt * 16 + m) * 32 + quad * 8);
    b1r[nt] = b1[nt * 16 + m];
  }
  __syncthreads();  // b1

  f32x4 z4 = {0.f, 0.f, 0.f, 0.f};
  f32x4 acc[8];
#pragma unroll
  for (int i = 0; i < 8; i++) acc[i] = z4;
  {
    bf16x8 a = *(const bf16x8*)(&sA[(rbase + m) * 48 + quad * 8]);
#pragma unroll
    for (int nt = 0; nt < 8; nt++)
      acc[nt] = __builtin_amdgcn_mfma_f32_16x16x32_bf16(a, w1f[nt], acc[nt], 0, 0, 0);
  }
#pragma unroll
  for (int nt = 0; nt < 8; nt++) {
#pragma unroll
    for (int r = 0; r < 4; r++) {
      float v = fmaxf(acc[nt][r] + b1r[nt], 0.f);
      unsigned int lo = f2bf(v);
      unsigned int hi = __shfl_xor(lo, 1, 64);
      if ((m & 1) == 0) {
        int rr = rbase + quad * 4 + r;
        *(unsigned int*)&sMid[rr * 136 + nt * 16 + m] = lo | (hi << 16);
      }
    }
  }
  bf16x8 w2f[8];
  float b2r[2];
#pragma unroll
  for (int ct = 0; ct < 2; ct++) {
    b2r[ct] = b2[w * 32 + ct * 16 + m];
#pragma unroll
    for (int kb = 0; kb < 4; kb++)
      w2f[ct * 4 + kb] = *(const bf16x8*)(w2t + (size_t)(w * 32 + ct * 16 + m) * 128 + kb * 32 + quad * 8);
  }
  __syncthreads();  // b2

  f32x4 acc2[8];
#pragma unroll
  for (int i = 0; i < 8; i++) acc2[i] = z4;
#pragma unroll
  for (int rt = 0; rt < 4; rt++) {
#pragma unroll
    for (int kb = 0; kb < 4; kb++) {
      bf16x8 a = *(const bf16x8*)(&sMid[(rt * 16 + m) * 136 + kb * 32 + quad * 8]);
      acc2[rt * 2 + 0] = __builtin_amdgcn_mfma_f32_16x16x32_bf16(a, w2f[kb], acc2[rt * 2 + 0], 0, 0, 0);
      acc2[rt * 2 + 1] = __builtin_amdgcn_mfma_f32_16x16x32_bf16(a, w2f[4 + kb], acc2[rt * 2 + 1], 0, 0, 0);
    }
  }
  __syncthreads();  // b3

#pragma unroll
  for (int rt = 0; rt < 4; rt++) {
#pragma unroll
    for (int ct = 0; ct < 2; ct++) {
#pragma unroll
      for (int r = 0; r < 4; r++) {
        float v = acc2[rt * 2 + ct][r] + b2r[ct];
        unsigned int lo = f2bf(v);
        unsigned int hi = __shfl_xor(lo, 1, 64);
        if ((m & 1) == 0) {
          int rr = rt * 16 + quad * 4 + r;
          int col = w * 32 + ct * 16 + m;
          *(unsigned int*)&sMid[rr * 136 + col] = lo | (hi << 16);
        }
      }
    }
  }
  __syncthreads();  // b4
  // contiguous write (plain stores: NT regressed 99->106 in r17)
#pragma unroll
  for (int i = 0; i < 4; i++) {
    int idx = t + 256 * i; int r = idx >> 4, c = idx & 15;
    *(uint4*)(e_perm + (size_t)(s0 + r) * 128 + c * 8) = *(const uint4*)&sMid[r * 136 + c * 8];
  }
}

// ---------------- aggregate v6: one node per 64-thread block ----------------
// z[n] = bf16( hb[n] + sum_{e->n} relu(hb[src]+e) ).  Block = 1 wave = 1 node
// -> block retires when its node finishes (no intra-block degree imbalance).
// Quarter-wave per edge: quarter q walks slots s0+q, s0+q+4,...; lane owns
// 8 cols (u16x8 = 16B). Cross-quarter shfl reduce at the end.
__global__ __launch_bounds__(64) void aggregate_k(const u16* __restrict__ hb,
                                                  const u16* __restrict__ e_perm,
                                                  const int* __restrict__ offs,
                                                  const int* __restrict__ csr_src,
                                                  u16* __restrict__ z, int n) {
  int node = blockIdx.x;
  if (node >= n) return;
  int lane = threadIdx.x;
  int q = lane >> 4, li = lane & 15;  // quarter, lane-in-quarter; cols li*8..+7
  int s0 = offs[node], s1 = offs[node + 1];
  float a[8];
#pragma unroll
  for (int j = 0; j < 8; j++) a[j] = 0.f;
  int s = s0 + q;
  for (; s + 8 <= s1; s += 8) {  // edges s and s+4, both valid
    int v0 = csr_src[s], v1 = csr_src[s + 4];
    u16x8 h0 = *(const u16x8*)(hb + (size_t)v0 * 128 + li * 8);
    u16x8 e0 = *(const u16x8*)(e_perm + (size_t)s * 128 + li * 8);
    u16x8 h1 = *(const u16x8*)(hb + (size_t)v1 * 128 + li * 8);
    u16x8 e1 = *(const u16x8*)(e_perm + (size_t)(s + 4) * 128 + li * 8);
#pragma unroll
    for (int j = 0; j < 8; j++) {
      a[j] += fmaxf(bf2f(h0[j]) + bf2f(e0[j]), 0.f);
      a[j] += fmaxf(bf2f(h1[j]) + bf2f(e1[j]), 0.f);
    }
  }
  for (; s < s1; s += 4) {
    int v = csr_src[s];
    u16x8 hv = *(const u16x8*)(hb + (size_t)v * 128 + li * 8);
    u16x8 ev = *(const u16x8*)(e_perm + (size_t)s * 128 + li * 8);
#pragma unroll
    for (int j = 0; j < 8; j++) a[j] += fmaxf(bf2f(hv[j]) + bf2f(ev[j]), 0.f);
  }
#pragma unroll
  for (int j = 0; j < 8; j++) {
    a[j] += __shfl_xor(a[j], 16, 64);
    a[j] += __shfl_xor(a[j], 32, 64);
  }
  if (q == 0) {
    u16x8 hv = *(const u16x8*)(hb + (size_t)node * 128 + li * 8);
    u16x8 o;
#pragma unroll
    for (int j = 0; j < 8; j++) o[j] = f2bf(bf2f(hv[j]) + a[j]);
    *(u16x8*)(z + (size_t)node * 128 + li * 8) = o;
  }
}

// ---------------- conv MLP v2: col-split GEMMs, weights in registers --------
// hb = bf16( relu(BN(relu(z@W1+b1)@W2+b2)) ).
__global__ __launch_bounds__(256) void conv_mlp(const u16* __restrict__ zb,
                                                u16* __restrict__ hb,
                                                const u16* __restrict__ w1t, const u16* __restrict__ w2t,
                                                const float* __restrict__ b1, const float* __restrict__ b2,
                                                const float* __restrict__ gam, const float* __restrict__ bet,
                                                int n) {
  __shared__ alignas(16) u16 sZ[64 * 136];
  __shared__ alignas(16) u16 sMid[64 * 136];
  int t = threadIdx.x;
  int lane = t & 63, w = t >> 6, m = lane & 15, quad = lane >> 4;
  int row0 = blockIdx.x * 64;
#pragma unroll
  for (int i = 0; i < 4; i++) {
    int idx = t + 256 * i; int r = idx >> 4, c = idx & 15;
    int grow = row0 + r; if (grow > n - 1) grow = n - 1;
    *(uint4*)&sZ[r * 136 + c * 8] = *(const uint4*)(zb + (size_t)grow * 128 + c * 8);
  }
  bf16x8 w1f[8];
  float b1r[2];
#pragma unroll
  for (int ct = 0; ct < 2; ct++) {
    b1r[ct] = b1[w * 32 + ct * 16 + m];
#pragma unroll
    for (int kb = 0; kb < 4; kb++)
      w1f[ct * 4 + kb] = *(const bf16x8*)(w1t + (size_t)(w * 32 + ct * 16 + m) * 128 + kb * 32 + quad * 8);
  }
  __syncthreads();  // b1: sZ complete

  f32x4 z4 = {0.f, 0.f, 0.f, 0.f};
  f32x4 acc[8];  // [rt*2+ct]
#pragma unroll
  for (int i = 0; i < 8; i++) acc[i] = z4;
#pragma unroll
  for (int rt = 0; rt < 4; rt++) {
#pragma unroll
    for (int kb = 0; kb < 4; kb++) {
      bf16x8 a = *(const bf16x8*)(&sZ[(rt * 16 + m) * 136 + kb * 32 + quad * 8]);
      acc[rt * 2 + 0] = __builtin_amdgcn_mfma_f32_16x16x32_bf16(a, w1f[kb], acc[rt * 2 + 0], 0, 0, 0);
      acc[rt * 2 + 1] = __builtin_amdgcn_mfma_f32_16x16x32_bf16(a, w1f[4 + kb], acc[rt * 2 + 1], 0, 0, 0);
    }
  }
#pragma unroll
  for (int rt = 0; rt < 4; rt++) {
#pragma unroll
    for (int ct = 0; ct < 2; ct++) {
#pragma unroll
      for (int r = 0; r < 4; r++) {
        float v = fmaxf(acc[rt * 2 + ct][r] + b1r[ct], 0.f);
        unsigned int lo = f2bf(v);
        unsigned int hi = __shfl_xor(lo, 1, 64);
        if ((m & 1) == 0) {
          int rr = rt * 16 + quad * 4 + r;
          int col = w * 32 + ct * 16 + m;
          *(unsigned int*)&sMid[rr * 136 + col] = lo | (hi << 16);
        }
      }
    }
  }
  bf16x8 w2f[8];
  float b2r[2], gamr[2], betr[2];
#pragma unroll
  for (int ct = 0; ct < 2; ct++) {
    int col = w * 32 + ct * 16 + m;
    b2r[ct] = b2[col]; gamr[ct] = gam[col]; betr[ct] = bet[col];
#pragma unroll
    for (int kb = 0; kb < 4; kb++)
      w2f[ct * 4 + kb] = *(const bf16x8*)(w2t + (size_t)col * 128 + kb * 32 + quad * 8);
  }
  __syncthreads();  // b2: sMid complete

  f32x4 acc2[8];
#pragma unroll
  for (int i = 0; i < 8; i++) acc2[i] = z4;
#pragma unroll
  for (int rt = 0; rt < 4; rt++) {
#pragma unroll
    for (int kb = 0; kb < 4; kb++) {
      bf16x8 a = *(const bf16x8*)(&sMid[(rt * 16 + m) * 136 + kb * 32 + quad * 8]);
      acc2[rt * 2 + 0] = __builtin_amdgcn_mfma_f32_16x16x32_bf16(a, w2f[kb], acc2[rt * 2 + 0], 0, 0, 0);
      acc2[rt * 2 + 1] = __builtin_amdgcn_mfma_f32_16x16x32_bf16(a, w2f[4 + kb], acc2[rt * 2 + 1], 0, 0, 0);
    }
  }
  const float bns = 0.99999500003749983f;  // 1/sqrt(1+1e-5)
#pragma unroll
  for (int rt = 0; rt < 4; rt++) {
#pragma unroll
    for (int ct = 0; ct < 2; ct++) {
      int col = w * 32 + ct * 16 + m;
#pragma unroll
      for (int r = 0; r < 4; r++) {
        int grow = row0 + rt * 16 + quad * 4 + r;
        if (grow < n) {
          float v = acc2[rt * 2 + ct][r] + b2r[ct];
          v = v * bns * gamr[ct] + betr[ct];
          hb[(size_t)grow * 128 + col] = f2bf(fmaxf(v, 0.f));
        }
      }
    }
  }
}

// ---------------- gate: gate[n] = relu(hb@W1+b1)@w2 + b2, 16 nodes/block ----
__global__ __launch_bounds__(256) void gate_k(const u16* __restrict__ hb, const float* __restrict__ w1,
                                              const float* __restrict__ b1, const float* __restrict__ w2,
                                              const float* __restrict__ b2, float* __restrict__ gate) {
  __shared__ alignas(16) u16 sW1[128 * 64];
  __shared__ alignas(16) u16 sRow[16 * 128];
  int t = threadIdx.x;
  int nbase = blockIdx.x * 16;
#pragma unroll
  for (int i = 0; i < 8; i++) {
    int idx = t + 256 * i;  // 2048 chunks-of-4 = 8192 weights
    float4 v = *(const float4*)(w1 + (size_t)idx * 4);
    ushort4 o; o.x = f2bf(v.x); o.y = f2bf(v.y); o.z = f2bf(v.z); o.w = f2bf(v.w);
    *(ushort4*)&sW1[idx * 4] = o;
  }
  {
    int r = t >> 4, c = t & 15;  // 16 rows x 16 uint4
    *(uint4*)&sRow[r * 128 + c * 8] = *(const uint4*)(hb + (size_t)(nbase + r) * 128 + c * 8);
  }
  __syncthreads();
  int lane = t & 63, w = t >> 6;
  float b1v = b1[lane], w2v = w2[lane], b2v = b2[0];
#pragma unroll
  for (int j = 0; j < 4; j++) {
    int node = w * 4 + j;
    float s = 0.f;
#pragma unroll 8
    for (int k = 0; k < 128; k++) s += bf2f(sRow[node * 128 + k]) * bf2f(sW1[k * 64 + lane]);
    float hid = fmaxf(s + b1v, 0.f);
    float p = hid * w2v;
    for (int d = 32; d; d >>= 1) p += __shfl_xor(p, d, 64);
    if (lane == 0) gate[nbase + node] = p + b2v;
  }
}

// ---------------- pooled segment softmax (256 threads, parity-split) --------
__global__ __launch_bounds__(256) void pool_k(const float* __restrict__ gate,
                                              const u16* __restrict__ hb,
                                              const int* __restrict__ goffs,
                                              float* __restrict__ gpool) {
  int g = blockIdx.x, t = threadIdx.x;  // 256 threads
  int s0 = goffs[g], s1 = goffs[g + 1];
  int lane = t & 63, w = t >> 6;
  __shared__ float red[4];
  __shared__ float fin[2][128];
  float mx = -3.4e38f;
  for (int i = s0 + t; i < s1; i += 256) mx = fmaxf(mx, gate[i]);
  for (int d = 32; d; d >>= 1) mx = fmaxf(mx, __shfl_xor(mx, d, 64));
  if (lane == 0) red[w] = mx;
  __syncthreads();
  mx = fmaxf(fmaxf(red[0], red[1]), fmaxf(red[2], red[3]));
  __syncthreads();
  float sm = 0.f;
  for (int i = s0 + t; i < s1; i += 256) sm += __expf(gate[i] - mx);
  for (int d = 32; d; d >>= 1) sm += __shfl_xor(sm, d, 64);
  if (lane == 0) red[w] = sm;
  __syncthreads();
  sm = red[0] + red[1] + red[2] + red[3];
  int g2 = t >> 7, tc = t & 127;
  float acc = 0.f;
  for (int i = s0 + g2; i < s1; i += 2)
    acc += __expf(gate[i] - mx) * bf2f(hb[(size_t)i * 128 + tc]);
  fin[g2][tc] = acc;
  __syncthreads();
  if (t < 128) gpool[g * 128 + t] = (s1 > s0) ? (fin[0][t] + fin[1][t]) / sm : 0.f;
}

// ---------------- head ------------------------------------------------------
__global__ __launch_bounds__(128) void head_k(const float* __restrict__ gpool,
                                              const float* __restrict__ w1, const float* __restrict__ b1,
                                              const float* __restrict__ w2, const float* __restrict__ b2,
                                              float* __restrict__ out) {
  int g = blockIdx.x, t = threadIdx.x;  // 128
  __shared__ float sg[128];
  __shared__ float shid[128];
  sg[t] = gpool[g * 128 + t];
  __syncthreads();
  float s = 0.f;
  for (int k = 0; k < 128; k++) s += sg[k] * w1[k * 128 + t];
  shid[t] = fmaxf(s + b1[t], 0.f);
  __syncthreads();
  if (t < 5) {
    float o = b2[t];
    for (int k = 0; k < 128; k++) o += shid[k] * w2[k * 5 + t];
    out[g * 5 + t] = o;
  }
}

// ---------------- launcher ---------------------------------------------------
extern "C" void kernel_launch(void* const* d_in, const int* in_sizes, int n_in,
                              void* d_out, int out_size, void* d_ws, size_t ws_size,
                              hipStream_t stream) {
  const int N = NNODES, E = NEDGES, G = NGRAPH;
  const float* x = (const float*)d_in[0];
  const float* edge_attr = (const float*)d_in[1];
  const float* node_w = (const float*)d_in[2];
  const float* node_b = (const float*)d_in[3];
  const float* edge_w1 = (const float*)d_in[4];
  const float* edge_b1 = (const float*)d_in[5];
  const float* edge_w2 = (const float*)d_in[6];
  const float* edge_b2 = (const float*)d_in[7];
  const float* conv_w1 = (const float*)d_in[8];
  const float* conv_b1 = (const float*)d_in[9];
  const float* conv_w2 = (const float*)d_in[10];
  const float* conv_b2 = (const float*)d_in[11];
  const float* bn_gamma = (const float*)d_in[12];
  const float* bn_beta = (const float*)d_in[13];
  const float* gate_w1 = (const float*)d_in[14];
  const float* gate_b1 = (const float*)d_in[15];
  const float* gate_w2 = (const float*)d_in[16];
  const float* gate_b2 = (const float*)d_in[17];
  const float* head_w1 = (const float*)d_in[18];
  const float* head_b1 = (const float*)d_in[19];
  const float* head_w2 = (const float*)d_in[20];
  const float* head_b2 = (const float*)d_in[21];
  const int* eidx = (const int*)d_in[22];
  const int* batch = (const int*)d_in[23];
  const int* esrc = eidx;
  const int* edst = eidx + E;

  char* wp = (char*)d_ws;
  auto alloc = [&](size_t bytes) { char* p = wp; wp += (bytes + 255) & ~(size_t)255; return p; };
  u16* e_perm = (u16*)alloc((size_t)E * 128 * 2);
  u16* hb = (u16*)alloc((size_t)(N + 16) * 128 * 2);  // +pad for gate tile overread
  u16* zb = (u16*)alloc((size_t)N * 128 * 2);
  float* gate = (float*)alloc((size_t)N * 4);
  float* gpool = (float*)alloc((size_t)G * 128 * 4);
  int* counts = (int*)alloc((size_t)N * 4);
  int* offs = (int*)alloc((size_t)(N + 1) * 4);
  int* cursor = (int*)alloc((size_t)N * 4);
  int* csr_src = (int*)alloc((size_t)E * 4);
  int* csr_eid = (int*)alloc((size_t)E * 4);
  int* bsums = (int*)alloc(64 * 4);
  int* gcounts = (int*)alloc(G * 4);
  int* goffs = (int*)alloc((G + 1) * 4);
  u16* node_wt = (u16*)alloc(8192 * 2);
  u16* edge_w1t = (u16*)alloc(4096 * 2);
  u16* edge_w2t = (u16*)alloc(16384 * 2);
  u16* conv_w1t = (u16*)alloc(65536 * 2);
  u16* conv_w2t = (u16*)alloc(65536 * 2);

  size_t need = (size_t)(wp - (char*)d_ws);
  if (need > ws_size) {
    write_zero_f32<<<(out_size + 255) / 256, 256, 0, stream>>>((float*)d_out, out_size);
    return;
  }

  zero_counts<<<(N + 255) / 256, 256, 0, stream>>>(counts, N, gcounts, G);
  prep_weights<<<624, 256, 0, stream>>>(node_w, edge_w1, edge_w2, conv_w1, conv_w2,
                                        node_wt, edge_w1t, edge_w2t, conv_w1t, conv_w2t);
  hist_all<<<E / 256, 256, 0, stream>>>(edst, batch, counts, gcounts, N);
  scan_a<<<49, 256, 0, stream>>>(counts, bsums, N);
  scan_b<<<1, 64, 0, stream>>>(bsums, offs, 49, N);
  scan_c<<<49, 256, 0, stream>>>(counts, bsums, offs, cursor, N);
  gscan<<<1, 256, 0, stream>>>(gcounts, goffs);
  scatter_csr<<<E / 256, 256, 0, stream>>>(esrc, edst, cursor, csr_src, csr_eid);
  node_encode<<<(N + 63) / 64, 256, 0, stream>>>(x, node_wt, node_b, hb, N);
  edge_encode<<<E / 64, 256, 0, stream>>>(edge_attr, edge_w1t, edge_w2t, edge_b1, edge_b2,
                                          csr_eid, e_perm);
  for (int l = 0; l < 4; l++) {
    aggregate_k<<<N, 64, 0, stream>>>(hb, e_perm, offs, csr_src, zb, N);
    conv_mlp<<<(N + 63) / 64, 256, 0, stream>>>(zb, hb, conv_w1t + l * 16384, conv_w2t + l * 16384,
                                                conv_b1 + l * 128, conv_b2 + l * 128,
                                                bn_gamma + l * 128, bn_beta + l * 128, N);
  }
  gate_k<<<(N + 15) / 16, 256, 0, stream>>>(hb, gate_w1, gate_b1, gate_w2, gate_b2, gate);
  pool_k<<<G, 256, 0, stream>>>(gate, hb, goffs, gpool);
  head_k<<<G, 128, 0, stream>>>(gpool, head_w1, head_b1, head_w2, head_b2, (float*)d_out);
}